// Round 1
// baseline (426.283 us; speedup 1.0000x reference)
//
#include <hip/hip_runtime.h>

// Problem dims (fixed)
#define B_DIM  2
#define C_DIM  8
#define F_DIM  1024
#define T_DIM  256
#define CH_DIM 32
#define FH_DIM 4096
#define BT_DIM 512   // B*T

typedef __bf16 bf16x8 __attribute__((ext_vector_type(8)));
typedef __bf16 bf16x4 __attribute__((ext_vector_type(4)));
typedef float  f32x4  __attribute__((ext_vector_type(4)));

__device__ __forceinline__ void async16(const void* g, void* l) {
  __builtin_amdgcn_global_load_lds(
      (const __attribute__((address_space(1))) unsigned int*)g,
      (__attribute__((address_space(3))) unsigned int*)l, 16, 0, 0);
}

// ---------------------------------------------------------------------------
// Kernel 1: LayerNorm over F (per b,c,t) + affine, written TRANSPOSED:
//   hn[c][b*T + t][f]  (bf16)
// grid (T/16, C, B), block 256
// ---------------------------------------------------------------------------
__global__ void ln_kernel(const float* __restrict__ x,
                          const float* __restrict__ lnw,
                          const float* __restrict__ lnb,
                          __bf16* __restrict__ hn) {
  const int tb = blockIdx.x;      // t-chunk of 16
  const int c  = blockIdx.y;
  const int b  = blockIdx.z;
  const int tid = threadIdx.x;
  const int tx = tid & 15, ty = tid >> 4;
  const int t0 = tb * 16;

  const float* xp = x + (size_t)(b * C_DIM + c) * F_DIM * T_DIM;

  // ---- phase 1: stats per t over all f ----
  float s = 0.f, s2 = 0.f;
  for (int f = ty; f < F_DIM; f += 16) {
    float v = xp[f * T_DIM + t0 + tx];
    s += v; s2 += v * v;
  }
  __shared__ float ps[16][16], ps2[16][16];
  __shared__ float mean_s[16], rstd_s[16];
  ps[ty][tx] = s; ps2[ty][tx] = s2;
  __syncthreads();
  if (tid < 16) {
    float a = 0.f, a2 = 0.f;
    for (int j = 0; j < 16; ++j) { a += ps[j][tid]; a2 += ps2[j][tid]; }
    float mu  = a * (1.0f / F_DIM);
    float var = a2 * (1.0f / F_DIM) - mu * mu;
    mean_s[tid] = mu;
    rstd_s[tid] = rsqrtf(var + 1e-8f);
  }
  __syncthreads();

  // ---- phase 2: normalize + affine, transpose via LDS, write [bt][f] ----
  __shared__ float tile[64][17];
  __bf16* hp = hn + ((size_t)c * BT_DIM + b * T_DIM + t0) * F_DIM;
  for (int ff = 0; ff < 16; ++ff) {
    const int f0 = ff * 64;
#pragma unroll
    for (int it = 0; it < 4; ++it) {
      int e  = it * 256 + tid;
      int fi = e >> 4, ti = e & 15;
      float v = xp[(f0 + fi) * T_DIM + t0 + ti];
      v = (v - mean_s[ti]) * rstd_s[ti];
      v = v * lnw[c * F_DIM + f0 + fi] + lnb[c * F_DIM + f0 + fi];
      tile[fi][ti] = v;
    }
    __syncthreads();
#pragma unroll
    for (int it = 0; it < 4; ++it) {
      int e  = it * 256 + tid;
      int fx = e & 63, tw = e >> 6;   // tw in [0,16)
      hp[(size_t)tw * F_DIM + f0 + fx] = (__bf16)tile[fx][tw];
    }
    __syncthreads();
  }
}

// ---------------------------------------------------------------------------
// Kernel 2: batched GEMM.  C[m][n] = sum_k A[m][k] * Bt[n][k]
//   A: fp32 [batch][M][K] (weights, converted to bf16 at staging)
//   Bt: bf16 [batch][512][K] (activations, already k-minor)
//   CT=true : write C^T -> Co[batch][512][M]   (feeds next stage's B-operand)
//   CT=false: write C   -> Co[batch][M][512]
// 128x128 tile, BK=32, 4 waves, mfma 16x16x32 bf16. grid = MT*4*nbatch (=1024)
// Block-id decomposition keeps each (batch, m-panel) x all 4 n-tiles on one XCD.
// ---------------------------------------------------------------------------
template<bool CT, int MTBITS>
__global__ void gemm_kernel(const float* __restrict__ A,
                            const __bf16* __restrict__ Bmat,
                            __bf16* __restrict__ Co,
                            const int M, const int K) {
  const int MT  = 1 << MTBITS;
  const int bid = blockIdx.x;
  const int xcd = bid & 7;
  const int q   = bid >> 3;
  const int nt  = q & 3;
  const int idx = xcd * 32 + (q >> 2);   // 32 = nbatch*MT/8 for both instantiations
  const int batch = idx >> MTBITS;
  const int mt    = idx & (MT - 1);

  const int tid  = threadIdx.x;
  const int lane = tid & 63;
  const int wid  = tid >> 6;

  const float*  Ab = A    + (size_t)batch * M * K + (size_t)(mt * 128) * K;
  const __bf16* Bb = Bmat + (size_t)batch * BT_DIM * K + (size_t)(nt * 128) * K;

  __shared__ __align__(16) __bf16 As[128 * 32];
  __shared__ __align__(16) __bf16 Bs[128 * 32];

  f32x4 acc[4][4] = {};

  const int wm  = (wid >> 1) * 64;
  const int wn  = (wid & 1) * 64;
  const int lr  = lane & 15;
  const int lk8 = (lane >> 4) * 8;

  const int a_r = tid >> 3;          // + 32*i
  const int a_c = (tid & 7) * 4;
  const int b_r = wid * 32 + (lane >> 2);   // + 16*j
  const int b_c = (lane & 3) * 8;

  const int ksteps = K >> 5;
  for (int ks = 0; ks < ksteps; ++ks) {
    const int k0 = ks << 5;
    // A-tile: reg-staged fp32 -> bf16 -> LDS [128][32]
#pragma unroll
    for (int i = 0; i < 4; ++i) {
      const int row = a_r + 32 * i;
      float4 av = *(const float4*)(Ab + (size_t)row * K + k0 + a_c);
      bf16x4 bv;
      bv[0] = (__bf16)av.x; bv[1] = (__bf16)av.y;
      bv[2] = (__bf16)av.z; bv[3] = (__bf16)av.w;
      *(bf16x4*)(&As[row * 32 + a_c]) = bv;
    }
    // B-tile: async global->LDS, 16B/lane, linear [128][32]
#pragma unroll
    for (int j = 0; j < 2; ++j) {
      const __bf16* g = Bb + (size_t)(b_r + 16 * j) * K + k0 + b_c;
      async16(g, &Bs[(wid * 32 + 16 * j) * 32]);
    }
    __syncthreads();

    bf16x8 af[4], bfr[4];
#pragma unroll
    for (int mi = 0; mi < 4; ++mi)
      af[mi] = *(const bf16x8*)(&As[(wm + mi * 16 + lr) * 32 + lk8]);
#pragma unroll
    for (int ni = 0; ni < 4; ++ni)
      bfr[ni] = *(const bf16x8*)(&Bs[(wn + ni * 16 + lr) * 32 + lk8]);
#pragma unroll
    for (int mi = 0; mi < 4; ++mi)
#pragma unroll
      for (int ni = 0; ni < 4; ++ni)
        acc[mi][ni] = __builtin_amdgcn_mfma_f32_16x16x32_bf16(af[mi], bfr[ni], acc[mi][ni], 0, 0, 0);
    __syncthreads();
  }

  // epilogue: C/D frag map: col = lane&15, row = (lane>>4)*4 + reg
  const int col  = lane & 15;
  const int rowb = (lane >> 4) * 4;
#pragma unroll
  for (int mi = 0; mi < 4; ++mi) {
#pragma unroll
    for (int ni = 0; ni < 4; ++ni) {
      const int m = mt * 128 + wm + mi * 16 + rowb;
      const int n = nt * 128 + wn + ni * 16 + col;
      if (CT) {
        bf16x4 o;
#pragma unroll
        for (int r = 0; r < 4; ++r) o[r] = (__bf16)acc[mi][ni][r];
        *(bf16x4*)(Co + (size_t)batch * BT_DIM * M + (size_t)n * M + m) = o;
      } else {
#pragma unroll
        for (int r = 0; r < 4; ++r)
          Co[(size_t)batch * M * BT_DIM + (size_t)(m + r) * BT_DIM + n] = (__bf16)acc[mi][ni][r];
      }
    }
  }
}

// ---------------------------------------------------------------------------
// Kernel 3: channel mix 8->32 + squared ReLU.
//   h2[d][bt][g] = relu( sum_c dw1[d][c] * Y1[c][bt][g] )^2
// grid 1024x256, thread = (bt, 8 g's)
// ---------------------------------------------------------------------------
__global__ void mix1_kernel(const __bf16* __restrict__ Y1,
                            const float* __restrict__ dw1,
                            __bf16* __restrict__ h2) {
  const int gidx = blockIdx.x * 256 + threadIdx.x;  // 512(bt) * 512(g/8)
  const int g8 = gidx & 511, bt = gidx >> 9;
  const int g0 = g8 * 8;

  float y[C_DIM][8];
#pragma unroll
  for (int c = 0; c < C_DIM; ++c) {
    bf16x8 v = *(const bf16x8*)(Y1 + ((size_t)c * BT_DIM + bt) * FH_DIM + g0);
#pragma unroll
    for (int j = 0; j < 8; ++j) y[c][j] = (float)v[j];
  }
  for (int d = 0; d < CH_DIM; ++d) {
    float s[8] = {0.f,0.f,0.f,0.f,0.f,0.f,0.f,0.f};
#pragma unroll
    for (int c = 0; c < C_DIM; ++c) {
      const float wv = dw1[d * C_DIM + c];
#pragma unroll
      for (int j = 0; j < 8; ++j) s[j] += wv * y[c][j];
    }
    bf16x8 o;
#pragma unroll
    for (int j = 0; j < 8; ++j) {
      float r = s[j] > 0.f ? s[j] : 0.f;
      o[j] = (__bf16)(r * r);
    }
    *(bf16x8*)(h2 + ((size_t)d * BT_DIM + bt) * FH_DIM + g0) = o;
  }
}

// ---------------------------------------------------------------------------
// Kernel 4: channel mix 32->8 + residual.
//   out[b][dd][f][t] = x[b][dd][f][t] + sum_d dw2[dd][d] * Y2[d][f][b*T+t]
// grid 4096x256, thread = 4 t's
// ---------------------------------------------------------------------------
__global__ void mix2_kernel(const float* __restrict__ x,
                            const __bf16* __restrict__ Y2,
                            const float* __restrict__ dw2,
                            float* __restrict__ out) {
  const int gidx = blockIdx.x * 256 + threadIdx.x;  // 2^20 threads
  const int t4 = gidx & 63;
  const int f  = (gidx >> 6) & 1023;
  const int dd = (gidx >> 16) & 7;
  const int b  = gidx >> 19;
  const int t0 = t4 * 4;

  const size_t oidx = ((size_t)(b * C_DIM + dd) * F_DIM + f) * T_DIM + t0;
  float4 acc = *(const float4*)(x + oidx);
  for (int d = 0; d < CH_DIM; ++d) {
    const float wv = dw2[dd * CH_DIM + d];
    bf16x4 v = *(const bf16x4*)(Y2 + ((size_t)d * F_DIM + f) * BT_DIM + b * T_DIM + t0);
    acc.x += wv * (float)v[0];
    acc.y += wv * (float)v[1];
    acc.z += wv * (float)v[2];
    acc.w += wv * (float)v[3];
  }
  *(float4*)(out + oidx) = acc;
}

// ---------------------------------------------------------------------------
extern "C" void kernel_launch(void* const* d_in, const int* in_sizes, int n_in,
                              void* d_out, int out_size, void* d_ws, size_t ws_size,
                              hipStream_t stream) {
  const float* x   = (const float*)d_in[0];
  const float* lnw = (const float*)d_in[1];
  const float* lnb = (const float*)d_in[2];
  const float* pw1 = (const float*)d_in[3];
  const float* dw1 = (const float*)d_in[4];
  const float* pw2 = (const float*)d_in[5];
  const float* dw2 = (const float*)d_in[6];
  float* out = (float*)d_out;

  char* ws = (char*)d_ws;
  // hn : [C][BT][F]  bf16  8 MB   @ 0        (dead after pw1 gemm)
  // Y1 : [C][BT][Fh] bf16  32 MB  @ 8 MB     (dead after mix1)
  // h2 : [Ch][BT][Fh] bf16 128 MB @ 40 MB
  // Y2 : [Ch][F][BT] bf16  32 MB  @ 0        (overlaps dead hn/Y1)
  __bf16* hn = (__bf16*)(ws);
  __bf16* Y1 = (__bf16*)(ws + (8ULL << 20));
  __bf16* h2 = (__bf16*)(ws + (40ULL << 20));
  __bf16* Y2 = (__bf16*)(ws);

  ln_kernel<<<dim3(T_DIM / 16, C_DIM, B_DIM), 256, 0, stream>>>(x, lnw, lnb, hn);
  // pw1: per c: [4096 x 1024] @ [1024 x 512] -> Y1^T [512][4096]
  gemm_kernel<true, 5><<<32 * 4 * C_DIM, 256, 0, stream>>>(pw1, hn, Y1, FH_DIM, F_DIM);
  mix1_kernel<<<(BT_DIM * (FH_DIM / 8)) / 256, 256, 0, stream>>>(Y1, dw1, h2);
  // pw2: per d: [1024 x 4096] @ [4096 x 512] -> Y2 [1024][512]
  gemm_kernel<false, 3><<<8 * 4 * CH_DIM, 256, 0, stream>>>(pw2, h2, Y2, F_DIM, FH_DIM);
  mix2_kernel<<<(B_DIM * C_DIM * F_DIM * (T_DIM / 4)) / 256, 256, 0, stream>>>(x, Y2, dw2, out);
}